// Round 8
// baseline (520.631 us; speedup 1.0000x reference)
//
#include <hip/hip_runtime.h>
#include <hip/hip_bf16.h>

typedef __hip_bfloat16 bf16;
typedef short bf16x8 __attribute__((ext_vector_type(8)));
typedef float f32x4 __attribute__((ext_vector_type(4)));
typedef unsigned int u32x4 __attribute__((ext_vector_type(4)));
typedef unsigned short us8 __attribute__((ext_vector_type(8)));

#define NEGV 1e9f

static constexpr int Bn = 32, Tn = 512, Dn = 256, On = 256, KFn = 8, Gn = 64;

__device__ __forceinline__ float bfs2f(unsigned short s) {
    unsigned u = ((unsigned)s) << 16; float f; __builtin_memcpy(&f, &u, 4); return f;
}
__device__ __forceinline__ unsigned short f2bfs(float f) {  // RNE
    unsigned u; __builtin_memcpy(&u, &f, 4);
    u = u + 0x7FFFu + ((u >> 16) & 1u);
    return (unsigned short)(u >> 16);
}
__device__ __forceinline__ float loadf(const void* p, int i, int fl) {
    return fl ? bfs2f(((const unsigned short*)p)[i]) : ((const float*)p)[i];
}
__device__ __forceinline__ int detect_flag(const void* x0) {
    const unsigned short* u = (const unsigned short*)x0;
    int bad = 0;
    for (int i = 0; i < 32; i++) {
        unsigned short v = u[2 * i];
        int e = (v >> 7) & 0xFF;
        if (!(v == 0 || (e >= 90 && e <= 150))) bad++;
    }
    return (bad == 0) ? 1 : 0;
}
// async global->LDS 16B/lane; LDS dest = wave-uniform base + lane*16.
__device__ __forceinline__ void gload16(const unsigned short* g, unsigned short* l) {
    __builtin_amdgcn_global_load_lds(
        (const __attribute__((address_space(1))) unsigned int*)(unsigned long long)g,
        (__attribute__((address_space(3))) unsigned int*)(unsigned int)(unsigned long long)l,
        16, 0, 0);
}

// ---------------------------------------------------------------------------
// k_prep: flag + pad masks + all weight conversions/splits, role by blockIdx.
// ---------------------------------------------------------------------------
__global__ void k_prep(const void* __restrict__ x0,
                       const void* __restrict__ qm, const void* __restrict__ vm,
                       const void* __restrict__ W_R, const void* __restrict__ W_Q,
                       const void* __restrict__ br, const void* __restrict__ bq,
                       const void* __restrict__ W2R, const void* __restrict__ W2Q,
                       const void* __restrict__ wmv, const void* __restrict__ wmq,
                       int* __restrict__ flag, float* __restrict__ padq, float* __restrict__ padv,
                       float* __restrict__ brf, float* __restrict__ bqf,
                       float* __restrict__ wmvf, float* __restrict__ wmqf,
                       unsigned short* __restrict__ W2Rh, unsigned short* __restrict__ W2Rl,
                       unsigned short* __restrict__ W2Qh, unsigned short* __restrict__ W2Ql,
                       unsigned short* __restrict__ Whr, unsigned short* __restrict__ Wlr,
                       unsigned short* __restrict__ Whq, unsigned short* __restrict__ Wlq) {
    const int fl = detect_flag(x0);
    const int bid = blockIdx.x, tid = threadIdx.x;
    if (bid == 0) {
        if (tid == 0) *flag = fl;
        brf[tid] = loadf(br, tid, fl);
        bqf[tid] = loadf(bq, tid, fl);
        if (tid < 64) { wmvf[tid] = loadf(wmv, tid, fl); wmqf[tid] = loadf(wmq, tid, fl); }
    } else if (bid <= 128) {
        int i = (bid - 1) * 256 + tid;  // 0..32767
        const unsigned char* qb = (const unsigned char*)qm;
        bool is32 = (qb[1] == 0);
        int j = i & 16383;
        const void* m = (i < 16384) ? qm : vm;
        float pv;
        if (is32) pv = ((const int*)m)[j] ? 0.f : 1.f;
        else      pv = ((const unsigned char*)m)[j] ? 0.f : 1.f;
        if (i < 16384) padq[j] = pv; else padv[j] = pv;
    } else if (bid <= 640) {
        int i = (bid - 129) * 256 + tid;  // 0..131071 over both W's
        const void* src = (i < 65536) ? W_R : W_Q;
        unsigned short* oh = (i < 65536) ? Whr : Whq;
        unsigned short* ol = (i < 65536) ? Wlr : Wlq;
        int j = i & 65535;
        float wv = loadf(src, j, fl);
        unsigned short h = f2bfs(wv);
        oh[j] = h;
        ol[j] = f2bfs(wv - bfs2f(h));
    } else {
        int i = (bid - 641) * 256 + tid;  // 0..32767 over both W2's
        int j = i & 16383;
        float wv = loadf(i < 16384 ? W2R : W2Q, j, fl);
        unsigned short h = f2bfs(wv);
        unsigned short l = f2bfs(wv - bfs2f(h));
        if (i < 16384) { W2Rh[j] = h; W2Rl[j] = l; }
        else           { W2Qh[j] = h; W2Ql[j] = l; }
    }
}

// ---------------------------------------------------------------------------
// k_perm: Upp[(a*8+k)*256+o] = U[f/512, f%512, k], f=a*256+o.
// Thread = (a,o): one coalesced 16B read of 8 k's, 8 coalesced 2B writes.
// ---------------------------------------------------------------------------
__global__ void k_perm(const void* __restrict__ U, const void* __restrict__ V,
                       unsigned short* __restrict__ Ud, unsigned short* __restrict__ Vd,
                       const int* __restrict__ flagp) {
    int j = blockIdx.x * 256 + threadIdx.x;  // 0..131071
    const void* src = blockIdx.y ? V : U;
    unsigned short* dst = blockIdx.y ? Vd : Ud;
    int a = j >> 8, o = j & 255;
    int f = a * 256 + o;
    int s0 = ((f >> 9) << 12) + ((f & 511) << 3);
    unsigned short kv[8];
    if (*flagp) {
        us8 v = *(const us8*)&((const unsigned short*)src)[s0];
#pragma unroll
        for (int k = 0; k < 8; ++k) kv[k] = v[k];
    } else {
#pragma unroll
        for (int k = 0; k < 8; ++k) kv[k] = f2bfs(((const float*)src)[s0 + k]);
    }
#pragma unroll
    for (int k = 0; k < 8; ++k) dst[(a * 8 + k) * 256 + o] = kv[k];
}

// ---------------------------------------------------------------------------
// k_xt: Xt[b][t][d] (hi/lo bf16) <- X[b][d*512 + t]. Vectorized 8-wide.
// ---------------------------------------------------------------------------
__global__ __launch_bounds__(256) void k_xt(
    const void* __restrict__ x0, const void* __restrict__ x1,
    unsigned short* __restrict__ X0h, unsigned short* __restrict__ X0l,
    unsigned short* __restrict__ X1h, unsigned short* __restrict__ X1l,
    const int* __restrict__ flagp) {
    __shared__ float tl[64][65];
    const int inp = blockIdx.z >> 5, b = blockIdx.z & 31;
    const void* src = inp ? x1 : x0;
    unsigned short* oh = inp ? X1h : X0h;
    unsigned short* ol = inp ? X1l : X0l;
    const int t0 = blockIdx.x * 64, d0 = blockIdx.y * 64;
    const int tid = threadIdx.x;
    const int fl = *flagp;
#pragma unroll
    for (int p = 0; p < 2; ++p) {
        int idx = p * 256 + tid;           // 0..511
        int r = idx >> 3, c8 = (idx & 7) * 8;  // r: d-row, c8: t col base
        size_t gi = ((size_t)b * 256 + d0 + r) * 512 + t0 + c8;
        if (fl) {
            us8 v = *(const us8*)&((const unsigned short*)src)[gi];
#pragma unroll
            for (int jj = 0; jj < 8; ++jj) tl[r][c8 + jj] = bfs2f(v[jj]);
        } else {
            float4 v0 = *(const float4*)&((const float*)src)[gi];
            float4 v1 = *(const float4*)&((const float*)src)[gi + 4];
            tl[r][c8 + 0] = v0.x; tl[r][c8 + 1] = v0.y; tl[r][c8 + 2] = v0.z; tl[r][c8 + 3] = v0.w;
            tl[r][c8 + 4] = v1.x; tl[r][c8 + 5] = v1.y; tl[r][c8 + 6] = v1.z; tl[r][c8 + 7] = v1.w;
        }
    }
    __syncthreads();
#pragma unroll
    for (int p = 0; p < 2; ++p) {
        int idx = p * 256 + tid;
        int r = idx >> 3, c8 = (idx & 7) * 8;  // r: t-row, c8: d col base
        us8 hv, lv;
#pragma unroll
        for (int jj = 0; jj < 8; ++jj) {
            float v = tl[c8 + jj][r];
            unsigned short h = f2bfs(v);
            hv[jj] = h;
            lv[jj] = f2bfs(v - bfs2f(h));
        }
        size_t go = ((size_t)b * 512 + t0 + r) * 256 + d0 + c8;
        *(us8*)&oh[go] = hv;
        *(us8*)&ol[go] = lv;
    }
}

// ---------------------------------------------------------------------------
// k_rq (MFMA): Rt[b][t][o] = relu(sum_d Xt[t,d]*W[o,d] - NEG*pad[t] + bias[o])
// as hi/lo planes. 128t x 128o block, 4 waves 2x2 (64x64 each), BK=32,
// 3-term hi/lo: Ah*Bh + Ah*Bl + Al*Bh into one f32 acc.
// ---------------------------------------------------------------------------
__global__ __launch_bounds__(256) void k_rq(
    const unsigned short* __restrict__ X0h, const unsigned short* __restrict__ X0l,
    const unsigned short* __restrict__ X1h, const unsigned short* __restrict__ X1l,
    const unsigned short* __restrict__ Whr, const unsigned short* __restrict__ Wlr,
    const unsigned short* __restrict__ Whq, const unsigned short* __restrict__ Wlq,
    const float* __restrict__ padq, const float* __restrict__ padv,
    const float* __restrict__ brf, const float* __restrict__ bqf,
    unsigned short* __restrict__ Rth, unsigned short* __restrict__ Rtl,
    unsigned short* __restrict__ Qth, unsigned short* __restrict__ Qtl) {
    __shared__ __align__(16) unsigned short lds[4][4096];  // Ah, Al, Bh, Bl (128x32 each)
    const int side = blockIdx.z >> 5, b = blockIdx.z & 31;
    const unsigned short* Ah = side ? X1h : X0h;
    const unsigned short* Al = side ? X1l : X0l;
    const unsigned short* Bh = side ? Whq : Whr;
    const unsigned short* Bl = side ? Wlq : Wlr;
    const float* pad = side ? padv : padq;
    const float* bias = side ? bqf : brf;
    unsigned short* Oh = side ? Qth : Rth;
    unsigned short* Ol = side ? Qtl : Rtl;
    const int t0 = blockIdx.y * 128, o0 = blockIdx.x * 128;
    const int tid = threadIdx.x, w = tid >> 6, lane = tid & 63;
    const int wm = w >> 1, wn = w & 1, lr = lane & 15, lk = lane >> 4;
    f32x4 acc[4][4];
#pragma unroll
    for (int i = 0; i < 4; i++)
#pragma unroll
        for (int j = 0; j < 4; j++)
#pragma unroll
            for (int q = 0; q < 4; q++) acc[i][j][q] = 0.f;

    for (int dc = 0; dc < 8; ++dc) {
        const int d0 = dc * 32;
        __syncthreads();
#pragma unroll
        for (int part = 0; part < 2; ++part) {
            const int s = w + part * 4;
            const size_t oA = ((size_t)(b * 512 + t0 + s * 16 + lr)) * 256 + d0 + lk * 8;
            const size_t oB = ((size_t)(o0 + s * 16 + lr)) * 256 + d0 + lk * 8;
            unsigned short* lb = &lds[0][s * 512];
            gload16(Ah + oA, lb);
            gload16(Al + oA, lb + 4096);
            gload16(Bh + oB, lb + 8192);
            gload16(Bl + oB, lb + 12288);
        }
        __syncthreads();
        bf16x8 ah[4], bh[4], bl[4], al[4];
#pragma unroll
        for (int f = 0; f < 4; ++f) {
            ah[f] = *(const bf16x8*)&lds[0][(wm * 4 + f) * 512 + lane * 8];
            bh[f] = *(const bf16x8*)&lds[2][(wn * 4 + f) * 512 + lane * 8];
        }
#pragma unroll
        for (int fa = 0; fa < 4; ++fa)
#pragma unroll
            for (int fc = 0; fc < 4; ++fc)
                acc[fa][fc] = __builtin_amdgcn_mfma_f32_16x16x32_bf16(ah[fa], bh[fc], acc[fa][fc], 0, 0, 0);
#pragma unroll
        for (int f = 0; f < 4; ++f)
            bl[f] = *(const bf16x8*)&lds[3][(wn * 4 + f) * 512 + lane * 8];
#pragma unroll
        for (int fa = 0; fa < 4; ++fa)
#pragma unroll
            for (int fc = 0; fc < 4; ++fc)
                acc[fa][fc] = __builtin_amdgcn_mfma_f32_16x16x32_bf16(ah[fa], bl[fc], acc[fa][fc], 0, 0, 0);
#pragma unroll
        for (int f = 0; f < 4; ++f)
            al[f] = *(const bf16x8*)&lds[1][(wm * 4 + f) * 512 + lane * 8];
#pragma unroll
        for (int fa = 0; fa < 4; ++fa)
#pragma unroll
            for (int fc = 0; fc < 4; ++fc)
                acc[fa][fc] = __builtin_amdgcn_mfma_f32_16x16x32_bf16(al[fa], bh[fc], acc[fa][fc], 0, 0, 0);
    }
    float bi[4];
#pragma unroll
    for (int fn = 0; fn < 4; ++fn) bi[fn] = bias[o0 + wn * 64 + fn * 16 + lr];
#pragma unroll
    for (int fm = 0; fm < 4; ++fm) {
        int tbase = t0 + wm * 64 + fm * 16 + lk * 4;
#pragma unroll
        for (int q = 0; q < 4; ++q) {
            int t = tbase + q;
            float pv = NEGV * pad[b * 512 + t];
#pragma unroll
            for (int fn = 0; fn < 4; ++fn) {
                int o = o0 + wn * 64 + fn * 16 + lr;
                float v = acc[fm][fn][q] - pv + bi[fn];
                v = v > 0.f ? v : 0.f;
                unsigned short h = f2bfs(v);
                size_t off = ((size_t)(b * 512 + t)) * 256 + o;
                Oh[off] = h;
                Ol[off] = f2bfs(v - bfs2f(h));
            }
        }
    }
}

// ---------------------------------------------------------------------------
// k_F: F[b,a,c] = sum_k (sum_o Upp[a*8+k,o]*R[c,o]) * (sum_o Vpp[a*8+k,o]*Q[c,o])
// 128m x 128c block, 512 threads = 8 waves (2m x 4c), wave tile 64m x 32c.
// acc = 64 VGPRs. LDS 48KB (48 slots x 1KB frag-major), gload_lds staged,
// 2 barriers/chunk. Epilogue: q-sum + shfl_xor(16) = k-reduction.
// ---------------------------------------------------------------------------
__global__ __launch_bounds__(512, 2) void k_F(
    const unsigned short* __restrict__ Upp, const unsigned short* __restrict__ Vpp,
    const unsigned short* __restrict__ Rh, const unsigned short* __restrict__ Rl,
    const unsigned short* __restrict__ Qh, const unsigned short* __restrict__ Ql,
    float* __restrict__ Fh, int half) {
    // slots: U 0-7, V 8-15, Rh 16-23, Rl 24-31, Qh 32-39, Ql 40-47
    __shared__ __align__(16) unsigned short lds[48][512];
    const int b = blockIdx.z;
    const int by = blockIdx.y;
    const int c0 = blockIdx.x * 128;
    const int m0 = half * 2048 + by * 128;
    const int tid = threadIdx.x;
    const int w = tid >> 6, lane = tid & 63;
    const int wm = w >> 2, wn = w & 3;
    const int lr = lane & 15, lk = lane >> 4;
    const size_t bTO = (size_t)b * Tn * On;

    const size_t aoff = (size_t)(m0 + w * 16 + lr) * 256 + lk * 8;
    const size_t boff = bTO + (size_t)(c0 + w * 16 + lr) * 256 + lk * 8;

    f32x4 d1[4][2], d2[4][2];
#pragma unroll
    for (int i = 0; i < 4; i++)
#pragma unroll
        for (int j = 0; j < 2; j++)
#pragma unroll
            for (int q = 0; q < 4; q++) { d1[i][j][q] = 0.f; d2[i][j][q] = 0.f; }

    for (int oc = 0; oc < 8; ++oc) {
        const int o0 = oc * 32;
        __syncthreads();
        gload16(Upp + aoff + o0, &lds[w][0]);
        gload16(Vpp + aoff + o0, &lds[8 + w][0]);
        gload16(Rh + boff + o0, &lds[16 + w][0]);
        gload16(Rl + boff + o0, &lds[24 + w][0]);
        gload16(Qh + boff + o0, &lds[32 + w][0]);
        gload16(Ql + boff + o0, &lds[40 + w][0]);
        __syncthreads();
        {   // phase 1: d1 += U x (Rh + Rl)
            bf16x8 ua[4], xh[2], xl[2];
#pragma unroll
            for (int f = 0; f < 4; ++f)
                ua[f] = *(const bf16x8*)&lds[wm * 4 + f][lane * 8];
#pragma unroll
            for (int f = 0; f < 2; ++f) {
                xh[f] = *(const bf16x8*)&lds[16 + wn * 2 + f][lane * 8];
                xl[f] = *(const bf16x8*)&lds[24 + wn * 2 + f][lane * 8];
            }
#pragma unroll
            for (int fa = 0; fa < 4; ++fa)
#pragma unroll
                for (int fc = 0; fc < 2; ++fc) {
                    d1[fa][fc] = __builtin_amdgcn_mfma_f32_16x16x32_bf16(ua[fa], xh[fc], d1[fa][fc], 0, 0, 0);
                    d1[fa][fc] = __builtin_amdgcn_mfma_f32_16x16x32_bf16(ua[fa], xl[fc], d1[fa][fc], 0, 0, 0);
                }
        }
        {   // phase 2: d2 += V x (Qh + Ql)
            bf16x8 va[4], xh[2], xl[2];
#pragma unroll
            for (int f = 0; f < 4; ++f)
                va[f] = *(const bf16x8*)&lds[8 + wm * 4 + f][lane * 8];
#pragma unroll
            for (int f = 0; f < 2; ++f) {
                xh[f] = *(const bf16x8*)&lds[32 + wn * 2 + f][lane * 8];
                xl[f] = *(const bf16x8*)&lds[40 + wn * 2 + f][lane * 8];
            }
#pragma unroll
            for (int fa = 0; fa < 4; ++fa)
#pragma unroll
                for (int fc = 0; fc < 2; ++fc) {
                    d2[fa][fc] = __builtin_amdgcn_mfma_f32_16x16x32_bf16(va[fa], xh[fc], d2[fa][fc], 0, 0, 0);
                    d2[fa][fc] = __builtin_amdgcn_mfma_f32_16x16x32_bf16(va[fa], xl[fc], d2[fa][fc], 0, 0, 0);
                }
        }
    }
    // epilogue: rows m = wm*64+fa*16+lk*4+q -> a = m>>3, k = m&7.
#pragma unroll
    for (int fa = 0; fa < 4; ++fa)
#pragma unroll
        for (int fc = 0; fc < 2; ++fc) {
            float s = d1[fa][fc][0] * d2[fa][fc][0] + d1[fa][fc][1] * d2[fa][fc][1]
                    + d1[fa][fc][2] * d2[fa][fc][2] + d1[fa][fc][3] * d2[fa][fc][3];
            s += __shfl_xor(s, 16);
            if ((lane & 16) == 0) {
                int a_loc = by * 16 + wm * 8 + fa * 2 + (lk >> 1);
                int c = c0 + wn * 32 + fc * 16 + lr;
                Fh[((size_t)b * 256 + a_loc) * Tn + c] = s;
            }
        }
}

// ---------------------------------------------------------------------------
// k_w2 (MFMA): WR[b,g,t] = sum_o W2[g,o]*R[t,o].  M=64(g) x N=128(t) block,
// 4 waves each 64g x 32t, K=256, BK=32, 3-term hi/lo. z = side.
// ---------------------------------------------------------------------------
__global__ __launch_bounds__(256) void k_w2(
    const unsigned short* __restrict__ W2Rh, const unsigned short* __restrict__ W2Rl,
    const unsigned short* __restrict__ W2Qh, const unsigned short* __restrict__ W2Ql,
    const unsigned short* __restrict__ Rth, const unsigned short* __restrict__ Rtl,
    const unsigned short* __restrict__ Qth, const unsigned short* __restrict__ Qtl,
    float* __restrict__ WRw, float* __restrict__ WQw) {
    // slots: Ah 0-3, Al 4-7, Bh 8-15, Bl 16-23
    __shared__ __align__(16) unsigned short lds[24][512];
    const int side = blockIdx.z, b = blockIdx.y, t0 = blockIdx.x * 128;
    const unsigned short* Ah = side ? W2Qh : W2Rh;
    const unsigned short* Al = side ? W2Ql : W2Rl;
    const unsigned short* Bh = side ? Qth : Rth;
    const unsigned short* Bl = side ? Qtl : Rtl;
    float* C = side ? WQw : WRw;
    const int tid = threadIdx.x, w = tid >> 6, lane = tid & 63;
    const int lr = lane & 15, lk = lane >> 4;
    const size_t bTO = (size_t)b * Tn * On;
    const size_t aoff = (size_t)(w * 16 + lr) * 256 + lk * 8;
    const size_t boff0 = bTO + (size_t)(t0 + (2 * w) * 16 + lr) * 256 + lk * 8;
    const size_t boff1 = boff0 + 16 * 256;
    f32x4 acc[4][2];
#pragma unroll
    for (int i = 0; i < 4; i++)
#pragma unroll
        for (int j = 0; j < 2; j++)
#pragma unroll
            for (int q = 0; q < 4; q++) acc[i][j][q] = 0.f;

    for (int oc = 0; oc < 8; ++oc) {
        const int o0 = oc * 32;
        __syncthreads();
        gload16(Ah + aoff + o0, &lds[w][0]);
        gload16(Al + aoff + o0, &lds[4 + w][0]);
        gload16(Bh + boff0 + o0, &lds[8 + 2 * w][0]);
        gload16(Bh + boff1 + o0, &lds[8 + 2 * w + 1][0]);
        gload16(Bl + boff0 + o0, &lds[16 + 2 * w][0]);
        gload16(Bl + boff1 + o0, &lds[16 + 2 * w + 1][0]);
        __syncthreads();
        bf16x8 ah[4], al[4], bh[2], bl[2];
#pragma unroll
        for (int f = 0; f < 4; ++f) {
            ah[f] = *(const bf16x8*)&lds[f][lane * 8];
            al[f] = *(const bf16x8*)&lds[4 + f][lane * 8];
        }
#pragma unroll
        for (int f = 0; f < 2; ++f) {
            bh[f] = *(const bf16x8*)&lds[8 + w * 2 + f][lane * 8];
            bl[f] = *(const bf16x8*)&lds[16 + w * 2 + f][lane * 8];
        }
#pragma unroll
        for (int fa = 0; fa < 4; ++fa)
#pragma unroll
            for (int fc = 0; fc < 2; ++fc) {
                acc[fa][fc] = __builtin_amdgcn_mfma_f32_16x16x32_bf16(ah[fa], bh[fc], acc[fa][fc], 0, 0, 0);
                acc[fa][fc] = __builtin_amdgcn_mfma_f32_16x16x32_bf16(ah[fa], bl[fc], acc[fa][fc], 0, 0, 0);
                acc[fa][fc] = __builtin_amdgcn_mfma_f32_16x16x32_bf16(al[fa], bh[fc], acc[fa][fc], 0, 0, 0);
            }
    }
    // epilogue: g = fa*16 + lk*4 + q; t = t0 + w*32 + fc*16 + lr
#pragma unroll
    for (int fa = 0; fa < 4; ++fa)
#pragma unroll
        for (int fc = 0; fc < 2; ++fc)
#pragma unroll
            for (int q = 0; q < 4; ++q) {
                int g = fa * 16 + lk * 4 + q;
                int t = t0 + w * 32 + fc * 16 + lr;
                C[((size_t)(b * Gn + g)) * Tn + t] = acc[fa][fc][q];
            }
}

// ---------------------------------------------------------------------------
// Mv[b,g,x] (+)= sum_{r in half} WQ[b,g,r]*F[r,x]; Mq likewise with WR.
// init=1 -> store (folds the zero-init).
// ---------------------------------------------------------------------------
__global__ __launch_bounds__(256) void k_md_acc(
    const float* __restrict__ WQw, const float* __restrict__ WRw,
    const float* __restrict__ F, float* __restrict__ Mv, float* __restrict__ Mq,
    int half, int init) {
    __shared__ float Wl1[32][68], Wl2[32][68], Fl[32][68];
    int b = blockIdx.y, x0 = blockIdx.x * 64;
    int tid = threadIdx.x, tx = tid & 15, ty = tid >> 4;
    float a1[4][4] = {}, a2[4][4] = {};
    const float* Fb = F + (size_t)b * 256 * Tn;
    for (int r0 = 0; r0 < 256; r0 += 32) {
#pragma unroll
        for (int p = 0; p < 8; p++) {
            int idx = p * 256 + tid; int c = idx & 31, g = idx >> 5;
            int rg = half * 256 + r0 + c;
            Wl1[c][g] = WQw[((size_t)b * Gn + g) * Tn + rg];
            Wl2[c][g] = WRw[((size_t)b * Gn + g) * Tn + rg];
        }
#pragma unroll
        for (int p = 0; p < 8; p++) {
            int idx = p * 256 + tid; int xx = idx & 63, c = idx >> 6;
            Fl[c][xx] = Fb[(size_t)(r0 + c) * Tn + x0 + xx];
        }
        __syncthreads();
#pragma unroll
        for (int kk = 0; kk < 32; kk++) {
            float4 w1 = *(const float4*)&Wl1[kk][ty * 4];
            float4 w2 = *(const float4*)&Wl2[kk][ty * 4];
            float4 xv = *(const float4*)&Fl[kk][tx * 4];
            float W1[4] = {w1.x, w1.y, w1.z, w1.w};
            float W2a[4] = {w2.x, w2.y, w2.z, w2.w};
            float Xv[4] = {xv.x, xv.y, xv.z, xv.w};
#pragma unroll
            for (int i = 0; i < 4; i++)
#pragma unroll
                for (int j = 0; j < 4; j++) {
                    a1[i][j] += W1[i] * Xv[j];
                    a2[i][j] += W2a[i] * Xv[j];
                }
        }
        __syncthreads();
    }
#pragma unroll
    for (int i = 0; i < 4; i++) {
        size_t off = ((size_t)b * Gn + ty * 4 + i) * Tn + x0 + tx * 4;
        if (init) {
            *(float4*)&Mv[off] = make_float4(a1[i][0], a1[i][1], a1[i][2], a1[i][3]);
            *(float4*)&Mq[off] = make_float4(a2[i][0], a2[i][1], a2[i][2], a2[i][3]);
        } else {
            float4 m1 = *(float4*)&Mv[off];
            float4 m2 = *(float4*)&Mq[off];
            m1.x += a1[i][0]; m1.y += a1[i][1]; m1.z += a1[i][2]; m1.w += a1[i][3];
            m2.x += a2[i][0]; m2.y += a2[i][1]; m2.z += a2[i][2]; m2.w += a2[i][3];
            *(float4*)&Mv[off] = m1;
            *(float4*)&Mq[off] = m2;
        }
    }
}

// ---------------------------------------------------------------------------
// k_tail: d1/d2 + dual softmax + final product, one block per batch.
// ---------------------------------------------------------------------------
__global__ __launch_bounds__(256) void k_tail(
    const float* __restrict__ WRw, const float* __restrict__ WQw,
    const float* __restrict__ Mv, const float* __restrict__ Mq,
    const float* __restrict__ wmvf, const float* __restrict__ wmqf,
    const float* __restrict__ padq, const float* __restrict__ padv,
    const unsigned short* __restrict__ Rh, const unsigned short* __restrict__ Rl,
    const unsigned short* __restrict__ Qh, const unsigned short* __restrict__ Ql,
    void* __restrict__ out, const int* __restrict__ flagp) {
    __shared__ float g1[512], g2[512], w1[64], w2[64];
    __shared__ float sm1[4], sm2[4], ss1[4], ss2[4];
    const int b = blockIdx.x, tid = threadIdx.x;
    if (tid < 64) { w1[tid] = wmvf[tid]; w2[tid] = wmqf[tid]; }
    __syncthreads();
    for (int x = tid; x < 512; x += 256) {
        float s1 = 0.f, s2 = 0.f;
        for (int g = 0; g < 64; ++g) {
            size_t off = ((size_t)b * 64 + g) * 512 + x;
            float m1 = WRw[off] + Mv[off]; m1 = m1 > 0.f ? m1 : 0.f;
            float m2 = WQw[off] + Mq[off]; m2 = m2 > 0.f ? m2 : 0.f;
            s1 += w1[g] * m1;
            s2 += w2[g] * m2;
        }
        g1[x] = s1 - NEGV * padq[b * 512 + x];
        g2[x] = s2 - NEGV * padv[b * 512 + x];
    }
    __syncthreads();
    float a0 = g1[tid], a1v = g1[tid + 256], b0 = g2[tid], b1v = g2[tid + 256];
    float m1 = fmaxf(a0, a1v), m2 = fmaxf(b0, b1v);
#pragma unroll
    for (int off = 32; off; off >>= 1) {
        m1 = fmaxf(m1, __shfl_xor(m1, off));
        m2 = fmaxf(m2, __shfl_xor(m2, off));
    }
    int wid = tid >> 6;
    if ((tid & 63) == 0) { sm1[wid] = m1; sm2[wid] = m2; }
    __syncthreads();
    m1 = fmaxf(fmaxf(sm1[0], sm1[1]), fmaxf(sm1[2], sm1[3]));
    m2 = fmaxf(fmaxf(sm2[0], sm2[1]), fmaxf(sm2[2], sm2[3]));
    float e10 = expf(a0 - m1), e11 = expf(a1v - m1);
    float e20 = expf(b0 - m2), e21 = expf(b1v - m2);
    float s1 = e10 + e11, s2 = e20 + e21;
#pragma unroll
    for (int off = 32; off; off >>= 1) {
        s1 += __shfl_xor(s1, off);
        s2 += __shfl_xor(s2, off);
    }
    if ((tid & 63) == 0) { ss1[wid] = s1; ss2[wid] = s2; }
    __syncthreads();
    s1 = ss1[0] + ss1[1] + ss1[2] + ss1[3];
    s2 = ss2[0] + ss2[1] + ss2[2] + ss2[3];
    float i1 = 1.f / s1, i2 = 1.f / s2;
    g1[tid] = e10 * i1; g1[tid + 256] = e11 * i1;
    g2[tid] = e20 * i2; g2[tid + 256] = e21 * i2;
    __syncthreads();
    const int o = tid;
    const size_t r0 = ((size_t)b * Tn + o) * On;
    const size_t r1 = ((size_t)b * Tn + o + 256) * On;
    float acc1 = 0.f, acc2 = 0.f;
    for (int u8 = 0; u8 < 32; ++u8) {
        u32x4 rh0 = *(const u32x4*)&Rh[r0 + u8 * 8];
        u32x4 rl0 = *(const u32x4*)&Rl[r0 + u8 * 8];
        u32x4 rh1 = *(const u32x4*)&Rh[r1 + u8 * 8];
        u32x4 rl1 = *(const u32x4*)&Rl[r1 + u8 * 8];
        u32x4 qh0 = *(const u32x4*)&Qh[r0 + u8 * 8];
        u32x4 ql0 = *(const u32x4*)&Ql[r0 + u8 * 8];
        u32x4 qh1 = *(const u32x4*)&Qh[r1 + u8 * 8];
        u32x4 ql1 = *(const u32x4*)&Ql[r1 + u8 * 8];
#pragma unroll
        for (int e = 0; e < 4; ++e) {
            int ulo = u8 * 8 + 2 * e, uhi = ulo + 1;
            float r0lo = bfs2f((unsigned short)(rh0[e] & 0xFFFF)) + bfs2f((unsigned short)(rl0[e] & 0xFFFF));
            float r0hi = bfs2f((unsigned short)(rh0[e] >> 16))   + bfs2f((unsigned short)(rl0[e] >> 16));
            float r1lo = bfs2f((unsigned short)(rh1[e] & 0xFFFF)) + bfs2f((unsigned short)(rl1[e] & 0xFFFF));
            float r1hi = bfs2f((unsigned short)(rh1[e] >> 16))   + bfs2f((unsigned short)(rl1[e] >> 16));
            acc1 += g1[2 * ulo] * r0lo + g1[2 * uhi] * r0hi;
            acc1 += g1[2 * ulo + 1] * r1lo + g1[2 * uhi + 1] * r1hi;
            float q0lo = bfs2f((unsigned short)(qh0[e] & 0xFFFF)) + bfs2f((unsigned short)(ql0[e] & 0xFFFF));
            float q0hi = bfs2f((unsigned short)(qh0[e] >> 16))   + bfs2f((unsigned short)(ql0[e] >> 16));
            float q1lo = bfs2f((unsigned short)(qh1[e] & 0xFFFF)) + bfs2f((unsigned short)(ql1[e] & 0xFFFF));
            float q1hi = bfs2f((unsigned short)(qh1[e] >> 16))   + bfs2f((unsigned short)(ql1[e] >> 16));
            acc2 += g2[2 * ulo] * q0lo + g2[2 * uhi] * q0hi;
            acc2 += g2[2 * ulo + 1] * q1lo + g2[2 * uhi + 1] * q1hi;
        }
    }
    float p = acc1 * acc2;
    if (*flagp) ((bf16*)out)[b * On + o] = __float2bfloat16(p);
    else        ((float*)out)[b * On + o] = p;
}

extern "C" void kernel_launch(void* const* d_in, const int* in_sizes, int n_in,
                              void* d_out, int out_size, void* d_ws, size_t ws_size,
                              hipStream_t stream) {
    (void)in_sizes; (void)n_in; (void)out_size; (void)ws_size;
    const void* x0  = d_in[0];
    const void* x1  = d_in[1];
    const void* qm  = d_in[2];
    const void* vm  = d_in[3];
    const void* W_R = d_in[4];
    const void* W_Q = d_in[5];
    const void* br  = d_in[6];
    const void* bq  = d_in[7];
    const void* U   = d_in[8];
    const void* V   = d_in[9];
    const void* W2R = d_in[10];
    const void* W2Q = d_in[11];
    const void* wmv = d_in[12];
    const void* wmq = d_in[13];

    float* ws = (float*)d_ws;
    int*   flag = (int*)ws;                       // 16
    float* padq = ws + 16;                        // 16384
    float* padv = padq + 16384;                   // 16384
    float* brf  = padv + 16384;                   // 256
    float* bqf  = brf + 256;                      // 256
    float* wmvf = bqf + 256;                      // 64
    float* wmqf = wmvf + 64;                      // 64
    unsigned short* W2Rh = (unsigned short*)(wmqf + 64);  // 16384 shorts each
    unsigned short* W2Rl = W2Rh + 16384;
    unsigned short* W2Qh = W2Rl + 16384;
    unsigned short* W2Ql = W2Qh + 16384;
    unsigned short* Whr = W2Ql + 16384;           // 65536 shorts each
    unsigned short* Wlr = Whr + 65536;
    unsigned short* Whq = Wlr + 65536;
    unsigned short* Wlq = Whq + 65536;
    unsigned short* Ubf = Wlq + 65536;            // 1048576 shorts each
    unsigned short* Vbf = Ubf + 1048576;
    unsigned short* Rth = Vbf + 1048576;          // 4194304 shorts each
    unsigned short* Rtl = Rth + 4194304;
    unsigned short* Qth = Rtl + 4194304;
    unsigned short* Qtl = Qth + 4194304;
    float* Mv   = (float*)(Qtl + 4194304);        // 1048576 floats each
    float* Mq   = Mv + 1048576;
    float* WRw  = Mq + 1048576;
    float* WQw  = WRw + 1048576;
    float* Fhalf = WQw + 1048576;                 // 4194304 floats
    // aliases (regions dead at time of use):
    unsigned short* Xt0h = (unsigned short*)Fhalf;            // 4194304 shorts
    unsigned short* Xt0l = Xt0h + 4194304;
    unsigned short* Xt1h = (unsigned short*)Mv;               // 4194304 shorts
    unsigned short* Xt1l = Xt1h + 4194304;
    // total ~72 MB

    k_prep<<<769, 256, 0, stream>>>(x0, qm, vm, W_R, W_Q, br, bq, W2R, W2Q, wmv, wmq,
                                    flag, padq, padv, brf, bqf, wmvf, wmqf,
                                    W2Rh, W2Rl, W2Qh, W2Ql, Whr, Wlr, Whq, Wlq);
    k_perm<<<dim3(512, 2), 256, 0, stream>>>(U, V, Ubf, Vbf, flag);
    k_xt<<<dim3(8, 4, 64), 256, 0, stream>>>(x0, x1, Xt0h, Xt0l, Xt1h, Xt1l, flag);
    k_rq<<<dim3(2, 4, 64), 256, 0, stream>>>(Xt0h, Xt0l, Xt1h, Xt1l,
                                             Whr, Wlr, Whq, Wlq,
                                             padq, padv, brf, bqf,
                                             Rth, Rtl, Qth, Qtl);
    k_w2<<<dim3(4, 32, 2), 256, 0, stream>>>(W2Rh, W2Rl, W2Qh, W2Ql,
                                             Rth, Rtl, Qth, Qtl, WRw, WQw);
    for (int half = 0; half < 2; half++) {
        k_F<<<dim3(4, 16, 32), 512, 0, stream>>>(Ubf, Vbf, Rth, Rtl, Qth, Qtl, Fhalf, half);
        k_md_acc<<<dim3(8, 32), 256, 0, stream>>>(WQw, WRw, Fhalf, Mv, Mq, half, half == 0);
    }
    k_tail<<<32, 256, 0, stream>>>(WRw, WQw, Mv, Mq, wmvf, wmqf, padq, padv,
                                   Rth, Rtl, Qth, Qtl, d_out, flag);
}